// Round 10
// baseline (222.432 us; speedup 1.0000x reference)
//
#include <hip/hip_runtime.h>

#define N_NODES 4096
#define N_EDGES 131072
#define BATCH   16
#define HDIM    16
#define FCDIM   20
#define BH      256              // BATCH*HDIM
#define ISD     0.17677669529663687f  // 1/sqrt(E/N) = 1/sqrt(32)
#define NSTRIP  32               // tmat i-strips (128 rows each)

// f4get with COMPILE-TIME k folds to a member read (runtime k would force scratch!)
__device__ __forceinline__ float f4get(const float4& v, int k) {
    return k == 0 ? v.x : (k == 1 ? v.y : (k == 2 ? v.z : v.w));
}

// ---------------- setup: ew, G[b][j][k], invF, zero d_out + cnt -------------
__global__ void setup_kernel(const float* __restrict__ F, const float* __restrict__ W_in,
                             const float* __restrict__ fc1_0, const float* __restrict__ fc2_0,
                             const float* __restrict__ fc1_1, const float* __restrict__ fc2_1,
                             float* __restrict__ ew, float* __restrict__ G,
                             float* __restrict__ invF, float* __restrict__ out144,
                             int* __restrict__ cnt) {
    int t = threadIdx.x;
    if (t < 6) {
        const float* fc1 = (t < 3) ? fc1_0 : fc1_1;
        const float* fc2 = (t < 3) ? fc2_0 : fc2_1;
        int ty = t % 3;
        float s = 0.f;
        for (int f = 0; f < FCDIM; ++f) {
            float v = fc1[ty * FCDIM + f];
            v = v > 0.f ? v : 0.f;
            s += v * fc2[f];
        }
        ew[t] = s;
    }
    for (int idx = t; idx < BATCH * 3 * HDIM; idx += 256) {
        int b = idx / 48, r = idx % 48, j = r / HDIM, k = r % HDIM;
        float s = 0.f;
        for (int i = 0; i < 3; ++i) s += F[b * 9 + i * 3 + j] * W_in[i * HDIM + k];
        G[idx] = s;
    }
    if (t < BATCH) {
        const float* f = F + t * 9;
        float a00=f[0],a01=f[1],a02=f[2],a10=f[3],a11=f[4],a12=f[5],a20=f[6],a21=f[7],a22=f[8];
        float det = a00*(a11*a22-a12*a21) - a01*(a10*a22-a12*a20) + a02*(a10*a21-a11*a20);
        float id = 1.f/det;
        float* o = invF + t*9;
        o[0]=(a11*a22-a12*a21)*id; o[1]=(a02*a21-a01*a22)*id; o[2]=(a01*a12-a02*a11)*id;
        o[3]=(a12*a20-a10*a22)*id; o[4]=(a00*a22-a02*a20)*id; o[5]=(a02*a10-a00*a12)*id;
        o[6]=(a10*a21-a11*a20)*id; o[7]=(a01*a20-a00*a21)*id; o[8]=(a00*a11-a01*a10)*id;
    }
    if (t < 144) out144[t] = 0.f;
    for (int i = t; i < N_NODES; i += 256) cnt[i] = 0;
}

// ---------------- fused: h0 compute (blocks 0..1023) + edge hist (1024..1535)
__global__ void h0_hist_kernel(const float* __restrict__ pos, const float* __restrict__ G,
                               float* __restrict__ h0,
                               const int* __restrict__ edst, int* __restrict__ cnt) {
    int bid = blockIdx.x;
    int t = threadIdx.x;
    if (bid < 1024) {
        int id = bid * 256 + t;
        int n  = id >> 6;
        int c4 = (id & 63) << 2;
        int b  = c4 >> 4;
        int k  = c4 & 15;
        float p0 = pos[n*3+0], p1 = pos[n*3+1], p2 = pos[n*3+2];
        const float* g = G + b*48 + k;
        float4 r;
        r.x = p0*g[0] + p1*g[16] + p2*g[32];
        r.y = p0*g[1] + p1*g[17] + p2*g[33];
        r.z = p0*g[2] + p1*g[18] + p2*g[34];
        r.w = p0*g[3] + p1*g[19] + p2*g[35];
        *(float4*)(h0 + n*BH + c4) = r;
    } else {
        int e = (bid - 1024) * 256 + t;
        if (e < N_EDGES) atomicAdd(&cnt[edst[e]], 1);
    }
}

// ---------------- CSR build -------------------------------------------------
__global__ void scan_kernel(const int* __restrict__ cnt, int* __restrict__ off,
                            int* __restrict__ cursor) {
    __shared__ int wsum[4];
    int t = threadIdx.x;
    int lane = t & 63, wave = t >> 6;
    int base = t * 16;
    int loc[16];
    int s = 0;
    #pragma unroll
    for (int i = 0; i < 16; ++i) { loc[i] = s; s += cnt[base + i]; }
    int pre = s;
    #pragma unroll
    for (int o = 1; o < 64; o <<= 1) {
        int v = __shfl_up(pre, o);
        if (lane >= o) pre += v;
    }
    if (lane == 63) wsum[wave] = pre;
    __syncthreads();
    int woff = 0;
    #pragma unroll
    for (int w = 0; w < 4; ++w) if (w < wave) woff += wsum[w];
    int excl = woff + pre - s;
    #pragma unroll
    for (int i = 0; i < 16; ++i) {
        int v = excl + loc[i];
        off[base + i] = v;
        cursor[base + i] = v;
    }
    if (t == 255) off[N_NODES] = excl + s;
}
__global__ void fill_kernel(const int* __restrict__ src, const int* __restrict__ dst,
                            const int* __restrict__ typ, int* __restrict__ cursor,
                            int* __restrict__ sedge) {
    int e = blockIdx.x * 256 + threadIdx.x;
    if (e < N_EDGES) {
        int p = atomicAdd(&cursor[dst[e]], 1);
        sedge[p] = src[e] | (typ[e] << 16);
    }
}

// ---------------- one GCN layer: gather+scale, @W, relu ---------------------
// 2 waves per dst node (half-row each, float2 lanes); grid 2048 -> 32 waves/CU
__global__ void layer_kernel(const float* __restrict__ h_in, float* __restrict__ h_out,
                             const int* __restrict__ off, const int* __restrict__ sedge,
                             const float* __restrict__ ew3, const float* __restrict__ W) {
    __shared__ float Wl[256];
    __shared__ float aggS[2][16*17 + 4];
    int t = threadIdx.x;
    Wl[t] = W[t];
    int wave = t >> 6, lane = t & 63;
    int node = wave >> 1;
    int half = wave & 1;
    int d = blockIdx.x * 2 + node;
    float e0 = ew3[0], e1 = ew3[1], e2 = ew3[2];
    int beg = off[d], end = off[d+1];
    int col = half * 128 + lane * 2;
    float2 acc = {0.f, 0.f};
    int it = beg;
    for (; it + 7 < end; it += 8) {
        int v[8]; float2 hv[8];
        #pragma unroll
        for (int u = 0; u < 8; ++u) v[u] = sedge[it + u];
        #pragma unroll
        for (int u = 0; u < 8; ++u)
            hv[u] = *(const float2*)(h_in + (v[u] & 0xFFFF) * BH + col);
        #pragma unroll
        for (int u = 0; u < 8; ++u) {
            int ty = v[u] >> 16;
            float wg = (ty == 0) ? e0 : (ty == 1 ? e1 : e2);
            acc.x += wg * hv[u].x; acc.y += wg * hv[u].y;
        }
    }
    for (; it < end; ++it) {
        int v = sedge[it];
        int ty = v >> 16;
        float wg = (ty == 0) ? e0 : (ty == 1 ? e1 : e2);
        float2 hv = *(const float2*)(h_in + (v & 0xFFFF) * BH + col);
        acc.x += wg * hv.x; acc.y += wg * hv.y;
    }
    int b = col >> 4, k0 = col & 15;
    aggS[node][b*17 + k0]     = acc.x * ISD;
    aggS[node][b*17 + k0 + 1] = acc.y * ISD;
    __syncthreads();
    int en = t >> 7, c2 = (t & 127) * 2;
    int eb = c2 >> 4, ek = c2 & 15;
    const float* arow = aggS[en] + eb * 17;
    float o0 = 0.f, o1 = 0.f;
    #pragma unroll
    for (int k = 0; k < 16; ++k) {
        float av = arow[k];
        o0 += av * Wl[k*16 + ek];
        o1 += av * Wl[k*16 + ek + 1];
    }
    int ed = blockIdx.x * 2 + en;
    float2 r;
    r.x = o0 > 0.f ? o0 : 0.f;
    r.y = o1 > 0.f ? o1 : 0.f;
    *(float2*)(h_out + ed*BH + c2) = r;
}

// ---------------- hout[n][b*3+p] = sum_k h2[n][b*16+k] * W_out[k][p] --------
__global__ void hout_kernel(const float* __restrict__ h2, const float* __restrict__ Wout,
                            float* __restrict__ hout) {
    __shared__ float Wo[48];
    int t = threadIdx.x;
    if (t < 48) Wo[t] = Wout[t];
    __syncthreads();
    int id = blockIdx.x * 256 + t;
    int n = id >> 4, b = id & 15;
    const float* hr = h2 + n*BH + b*HDIM;
    float s0=0.f, s1=0.f, s2=0.f;
    #pragma unroll
    for (int k = 0; k < 16; ++k) {
        float v = hr[k];
        s0 += v*Wo[k*3+0]; s1 += v*Wo[k*3+1]; s2 += v*Wo[k*3+2];
    }
    float* o = hout + n*48 + b*3;
    o[0]=s0; o[1]=s1; o[2]=s2;
}

// ---------------- a, c for first N edges ------------------------------------
__global__ void ac_kernel(const float* __restrict__ hout, const int* __restrict__ esrc,
                          const int* __restrict__ edst, const float* __restrict__ invF,
                          float* __restrict__ a, float* __restrict__ c) {
    __shared__ float iF[144];
    int t = threadIdx.x;
    if (t < 144) iF[t] = invF[t];
    __syncthreads();
    int id = blockIdx.x * 256 + t;
    int i = id >> 4, b = id & 15;
    int s = esrc[i], d = edst[i];
    float a0 = hout[s*48+b*3+0] - hout[d*48+b*3+0];
    float a1 = hout[s*48+b*3+1] - hout[d*48+b*3+1];
    float a2 = hout[s*48+b*3+2] - hout[d*48+b*3+2];
    float* ap = a + i*48 + b*3;
    ap[0]=a0; ap[1]=a1; ap[2]=a2;
    const float* m = iF + b*9;
    float* cp = c + i*48 + b*3;
    cp[0] = m[0]*a0 + m[1]*a1 + m[2]*a2;
    cp[1] = m[3]*a0 + m[4]*a1 + m[5]*a2;
    cp[2] = m[6]*a0 + m[7]*a1 + m[8]*a2;
}

// ---------------- stage 1: partial[s][col][j] = sum_{i in strip s} W2[i][j]*a[i][col]
// grid 1024 = 32 j-tiles(128 j) x 32 strips(128 rows); 512-thr blocks =
// 8 waves = 4 col-waves x 2 row-halves -> 4 blocks/CU = 32 waves/CU (100%
// wave slots; R9 was 16 waves/CU and VALU scaled linearly with waves).
// Lane owns 2 j (dwordx2 W2), wave owns 12 cols, half owns 64 rows.
// a-strip in LDS (lgkmcnt); 4-deep rotating W2 prefetch (16 buf VGPRs) keeps
// total hot set <=64 VGPR -> 8 waves/SIMD bin. Halves combine via recycled
// a-stage LDS. __launch_bounds__(512,8) enforces the 64-VGPR cap.
__global__ __launch_bounds__(512, 8)
void tmat_kernel(const float* __restrict__ W2, const float* __restrict__ a,
                 float* __restrict__ partial) {
    __shared__ float sa[128 * 48];   // 24 KB, reused as combine buffer
    int t = threadIdx.x;
    int lane = t & 63;
    int wave = t >> 6;          // 0..7
    int cw   = wave & 3;        // col-wave
    int rh   = wave >> 2;       // row half
    int cg   = cw * 12;
    int jb    = (blockIdx.x & 31) * 128;
    int strip = blockIdx.x >> 5;         // 0..31
    int i0    = strip * 128;
    // stage a-strip: 6144 floats = 1536 float4, 3 per thread
    {
        const float4* ga = (const float4*)(a + (size_t)i0 * 48);
        float4* la = (float4*)sa;
        la[t] = ga[t]; la[t + 512] = ga[t + 512]; la[t + 1024] = ga[t + 1024];
    }
    __syncthreads();
    int j  = jb + lane * 2;
    int r0 = rh * 64;
    const float* w2p = W2 + (size_t)(i0 + r0) * N_NODES + j;
    float4 acc[2][3];
    #pragma unroll
    for (int jj = 0; jj < 2; ++jj)
        #pragma unroll
        for (int q = 0; q < 3; ++q) acc[jj][q] = make_float4(0.f,0.f,0.f,0.f);
    float2 w[4];
    #pragma unroll
    for (int u = 0; u < 4; ++u)
        w[u] = *(const float2*)(w2p + (size_t)u * N_NODES);
    #pragma unroll 1
    for (int base = 0; base < 64; base += 4) {
        float2 wn[4];
        #pragma unroll
        for (int u = 0; u < 4; ++u) {
            int r = base + 4 + u; if (r > 63) r = 63;
            wn[u] = *(const float2*)(w2p + (size_t)r * N_NODES);
        }
        #pragma unroll
        for (int u = 0; u < 4; ++u) {
            const float* ar = &sa[(r0 + base + u) * 48 + cg];
            float4 x = *(const float4*)(ar);
            float4 y = *(const float4*)(ar + 4);
            float4 z = *(const float4*)(ar + 8);
            #pragma unroll
            for (int jj = 0; jj < 2; ++jj) {
                float wv = jj == 0 ? w[u].x : w[u].y;
                acc[jj][0].x += wv*x.x; acc[jj][0].y += wv*x.y;
                acc[jj][0].z += wv*x.z; acc[jj][0].w += wv*x.w;
                acc[jj][1].x += wv*y.x; acc[jj][1].y += wv*y.y;
                acc[jj][1].z += wv*y.z; acc[jj][1].w += wv*y.w;
                acc[jj][2].x += wv*z.x; acc[jj][2].y += wv*z.y;
                acc[jj][2].z += wv*z.z; acc[jj][2].w += wv*z.w;
            }
        }
        #pragma unroll
        for (int u = 0; u < 4; ++u) w[u] = wn[u];
    }
    // combine halves via recycled LDS: layout [col][128 j], float2 per lane
    __syncthreads();   // all a-reads done; safe to overwrite sa
    if (rh == 0) {
        #pragma unroll
        for (int c = 0; c < 12; ++c) {
            float2 v;
            v.x = f4get(acc[0][c >> 2], c & 3);
            v.y = f4get(acc[1][c >> 2], c & 3);
            *(float2*)&sa[(cg + c) * 128 + lane * 2] = v;
        }
    }
    __syncthreads();
    if (rh == 1) {
        float* pbase = partial + (size_t)strip * (48 * N_NODES) + jb;
        #pragma unroll
        for (int c = 0; c < 12; ++c) {
            float2 h0 = *(float2*)&sa[(cg + c) * 128 + lane * 2];
            float2 v;
            v.x = h0.x + f4get(acc[0][c >> 2], c & 3);
            v.y = h0.y + f4get(acc[1][c >> 2], c & 3);
            *(float2*)(pbase + (size_t)(cg + c) * N_NODES + lane * 2) = v;
        }
    }
}

// ---------------- fused reduce + stress: out[b,p,q] += sum_j (sum_s partial)*c
// grid 768 x 64: block covers 256 consecutive floats of one col (col uniform).
__global__ void reduce_stress_kernel(const float* __restrict__ partial,
                                     const float* __restrict__ c,
                                     float* __restrict__ out) {
    int t = threadIdx.x;                 // 0..63
    int x4 = blockIdx.x * 64 + t;        // float4 index, 49152 total
    int x  = x4 * 4;
    int col = x >> 12;                   // 0..47 (uniform within block)
    int j0  = x & 4095;
    float4 s = {0.f, 0.f, 0.f, 0.f};
    #pragma unroll 4
    for (int st = 0; st < NSTRIP; ++st) {
        float4 v = *(const float4*)(partial + (size_t)st * (48 * N_NODES) + x4 * 4);
        s.x += v.x; s.y += v.y; s.z += v.z; s.w += v.w;
    }
    int b = col / 3, p = col % 3;
    float sq0 = 0.f, sq1 = 0.f, sq2 = 0.f;
    #pragma unroll
    for (int u = 0; u < 4; ++u) {
        float tv = f4get(s, u);
        const float* cp = c + (size_t)(j0 + u) * 48 + b * 3;
        sq0 += tv * cp[0]; sq1 += tv * cp[1]; sq2 += tv * cp[2];
    }
    #pragma unroll
    for (int off = 32; off >= 1; off >>= 1) {
        sq0 += __shfl_xor(sq0, off);
        sq1 += __shfl_xor(sq1, off);
        sq2 += __shfl_xor(sq2, off);
    }
    if (t == 0) {
        atomicAdd(&out[b*9 + p*3 + 0], sq0);
        atomicAdd(&out[b*9 + p*3 + 1], sq1);
        atomicAdd(&out[b*9 + p*3 + 2], sq2);
    }
}

extern "C" void kernel_launch(void* const* d_in, const int* in_sizes, int n_in,
                              void* d_out, int out_size, void* d_ws, size_t ws_size,
                              hipStream_t stream) {
    const float* F     = (const float*)d_in[0];
    const float* pos   = (const float*)d_in[1];
    const int*   esrc  = (const int*)d_in[2];
    const int*   edst  = (const int*)d_in[3];
    const int*   etyp  = (const int*)d_in[4];
    const float* W_in  = (const float*)d_in[5];
    const float* fc1_0 = (const float*)d_in[6];
    const float* fc2_0 = (const float*)d_in[7];
    const float* W_0   = (const float*)d_in[8];
    const float* fc1_1 = (const float*)d_in[9];
    const float* fc2_1 = (const float*)d_in[10];
    const float* W_1   = (const float*)d_in[11];
    const float* W_out = (const float*)d_in[12];
    const float* w2    = (const float*)d_in[13];
    float* out = (float*)d_out;

    float* ws   = (float*)d_ws;
    float* ew   = ws;                     // 6
    float* G    = ws + 16;                // 768
    float* invF = ws + 800;               // 144
    float* bufA = ws + 1024;              // N*256
    float* bufB = bufA + N_NODES*BH;      // N*256
    float* hout = bufB + N_NODES*BH;      // N*48
    float* aArr = hout + N_NODES*48;      // N*48
    float* cArr = aArr + N_NODES*48;      // N*48
    float* tmat = cArr + N_NODES*48;      // N*48 (unused, kept for layout)
    int* cnt    = (int*)(tmat + N_NODES*48);
    int* off    = cnt + N_NODES;          // N+1
    int* cursor = off + N_NODES + 1;      // N
    int* sedge  = cursor + N_NODES;       // E
    float* partial = (float*)(sedge + N_EDGES);  // NSTRIP * N*48 (25 MB)

    setup_kernel<<<1, 256, 0, stream>>>(F, W_in, fc1_0, fc2_0, fc1_1, fc2_1, ew, G, invF, out, cnt);
    h0_hist_kernel<<<1536, 256, 0, stream>>>(pos, G, bufA, edst, cnt);
    scan_kernel<<<1, 256, 0, stream>>>(cnt, off, cursor);
    fill_kernel<<<512, 256, 0, stream>>>(esrc, edst, etyp, cursor, sedge);
    layer_kernel<<<2048, 256, 0, stream>>>(bufA, bufB, off, sedge, ew,     W_0);
    layer_kernel<<<2048, 256, 0, stream>>>(bufB, bufA, off, sedge, ew + 3, W_1);
    hout_kernel<<<256, 256, 0, stream>>>(bufA, W_out, hout);
    ac_kernel<<<256, 256, 0, stream>>>(hout, esrc, edst, invF, aArr, cArr);
    tmat_kernel<<<1024, 512, 0, stream>>>(w2, aArr, partial);
    reduce_stress_kernel<<<768, 64, 0, stream>>>(partial, cArr, out);
}